// Round 1
// baseline (567.738 us; speedup 1.0000x reference)
//
#include <hip/hip_runtime.h>
#include <hip/hip_bf16.h>

#define N_NODES   20000
#define N_EDGES   320000
#define DIM       256
#define N_GRAPHS  64
#define N_CLASSES 10

typedef short bf16x8 __attribute__((ext_vector_type(8)));
typedef float f32x4  __attribute__((ext_vector_type(4)));

__device__ __forceinline__ float b2f(ushort u) {
    return __uint_as_float(((unsigned)u) << 16);
}
__device__ __forceinline__ ushort f2b(float f) {
    unsigned u = __float_as_uint(f);
    u += 0x7FFF + ((u >> 16) & 1);   // round-to-nearest-even
    return (ushort)(u >> 16);
}

// ---------------- setup kernels ----------------

__global__ void k_convert_x(const float* __restrict__ x, ushort* __restrict__ xb, int n4) {
    int i = blockIdx.x * blockDim.x + threadIdx.x;
    if (i >= n4) return;
    const float4 v = ((const float4*)x)[i];
    ushort4 o; o.x = f2b(v.x); o.y = f2b(v.y); o.z = f2b(v.z); o.w = f2b(v.w);
    ((ushort4*)xb)[i] = o;
}

// Wt[n*256+k] = bf16(W[k*256+n])
__global__ void k_wt(const float* __restrict__ W, ushort* __restrict__ Wt) {
    int i = blockIdx.x * blockDim.x + threadIdx.x;   // 65536
    int n = i >> 8, k = i & 255;
    Wt[i] = f2b(W[k * 256 + n]);
}

__global__ void k_deg(const int* __restrict__ dst, int* __restrict__ deg) {
    int e = blockIdx.x * 256 + threadIdx.x;
    if (e < N_EDGES) atomicAdd(&deg[dst[e]], 1);
}

__global__ void k_counts(const int* __restrict__ batch, int* __restrict__ counts) {
    int i = blockIdx.x * 256 + threadIdx.x;
    if (i < N_NODES) atomicAdd(&counts[batch[i]], 1);
}

// dinv = rsqrt(in_deg + 1)   (the +1 is the self-loop)
__global__ void k_dinv(const int* __restrict__ deg, float* __restrict__ dinv) {
    int i = blockIdx.x * 256 + threadIdx.x;
    if (i < N_NODES) dinv[i] = rsqrtf((float)deg[i] + 1.0f);
}

// single-block exclusive scan of deg -> row_ptr[0..n]
__global__ void k_scan(const int* __restrict__ deg, int* __restrict__ row_ptr, int n) {
    __shared__ int sh[1024];
    int tid = threadIdx.x;
    int off = 0;
    int nchunk = (n + 1023) >> 10;
    for (int c = 0; c < nchunk; ++c) {
        int i = (c << 10) + tid;
        int v = (i < n) ? deg[i] : 0;
        sh[tid] = v;
        __syncthreads();
        for (int s = 1; s < 1024; s <<= 1) {
            int t = (tid >= s) ? sh[tid - s] : 0;
            __syncthreads();
            sh[tid] += t;
            __syncthreads();
        }
        if (i < n) row_ptr[i] = off + sh[tid] - v;   // exclusive
        off += sh[1023];
        __syncthreads();
    }
    if (tid == 0) row_ptr[n] = off;
}

__global__ void k_fill(const int* __restrict__ src, const int* __restrict__ dst,
                       const int* __restrict__ row_ptr, int* __restrict__ fill,
                       const float* __restrict__ dinv,
                       int* __restrict__ csr_src, float* __restrict__ csr_w) {
    int e = blockIdx.x * 256 + threadIdx.x;
    if (e >= N_EDGES) return;
    int s = src[e], d = dst[e];
    int pos = atomicAdd(&fill[d], 1);
    int idx = row_ptr[d] + pos;
    csr_src[idx] = s;
    csr_w[idx]   = dinv[s] * dinv[d];
}

// ---------------- GEMM: H[M,256] = Xb[M,256] @ W (Wt is W^T, bf16) ----------------
// wave computes 16 rows x 64 cols; block = 4 waves covering full N=256.
__global__ __launch_bounds__(256) void k_gemm(const ushort* __restrict__ Xb,
                                              const ushort* __restrict__ Wt,
                                              ushort* __restrict__ H) {
    int wave = threadIdx.x >> 6;
    int lane = threadIdx.x & 63;
    int m0 = blockIdx.x * 16;
    int n0 = wave * 64;
    int rl = lane & 15;
    int kq = (lane >> 4) * 8;

    const ushort* aptr = Xb + (size_t)(m0 + rl) * DIM + kq;
    f32x4 acc[4] = {};

#pragma unroll
    for (int kk = 0; kk < 8; ++kk) {
        int k0 = kk * 32;
        bf16x8 a = *(const bf16x8*)(aptr + k0);
#pragma unroll
        for (int nb = 0; nb < 4; ++nb) {
            const ushort* bptr = Wt + (size_t)(n0 + nb * 16 + rl) * DIM + k0 + kq;
            bf16x8 b = *(const bf16x8*)bptr;
            acc[nb] = __builtin_amdgcn_mfma_f32_16x16x32_bf16(a, b, acc[nb], 0, 0, 0);
        }
    }
    // C/D layout: col = lane&15, row = (lane>>4)*4 + reg
    int crow = m0 + (lane >> 4) * 4;
    int ccol = n0 + rl;
#pragma unroll
    for (int nb = 0; nb < 4; ++nb)
#pragma unroll
        for (int r = 0; r < 4; ++r)
            H[(size_t)(crow + r) * DIM + ccol + nb * 16] = f2b(acc[nb][r]);
}

// ---------------- aggregation: one wave per dst node ----------------
// mode 0: relu(acc+b) -> outb
// mode 1: relu(prev + acc + b) -> outb
// mode 2: atomicAdd pooled[batch[i]] += acc + b
__global__ __launch_bounds__(256) void k_agg(
    const ushort* __restrict__ H, const int* __restrict__ row_ptr,
    const int* __restrict__ csr_src, const float* __restrict__ csr_w,
    const float* __restrict__ dinv, const float* __restrict__ bias,
    const ushort* __restrict__ prev, ushort* __restrict__ outb,
    float* __restrict__ pooled, const int* __restrict__ batch, int mode) {
    int wave = threadIdx.x >> 6, lane = threadIdx.x & 63;
    int i = blockIdx.x * 4 + wave;
    if (i >= N_NODES) return;
    int f0 = lane * 4;
    float di = dinv[i];
    float wself = di * di;   // self-loop norm = 1/deg
    ushort4 hv = *(const ushort4*)(H + (size_t)i * DIM + f0);
    float a0 = b2f(hv.x) * wself, a1 = b2f(hv.y) * wself,
          a2 = b2f(hv.z) * wself, a3 = b2f(hv.w) * wself;
    int e1 = row_ptr[i + 1];
    for (int e = row_ptr[i]; e < e1; ++e) {
        int s = csr_src[e];
        float w = csr_w[e];
        ushort4 v = *(const ushort4*)(H + (size_t)s * DIM + f0);
        a0 += w * b2f(v.x); a1 += w * b2f(v.y);
        a2 += w * b2f(v.z); a3 += w * b2f(v.w);
    }
    const float4 bb = *(const float4*)(bias + f0);
    a0 += bb.x; a1 += bb.y; a2 += bb.z; a3 += bb.w;
    if (mode == 2) {
        int g = batch[i];
        float* p = pooled + (size_t)g * DIM + f0;
        atomicAdd(p + 0, a0); atomicAdd(p + 1, a1);
        atomicAdd(p + 2, a2); atomicAdd(p + 3, a3);
        return;
    }
    if (mode == 1) {
        ushort4 pv = *(const ushort4*)(prev + (size_t)i * DIM + f0);
        a0 += b2f(pv.x); a1 += b2f(pv.y); a2 += b2f(pv.z); a3 += b2f(pv.w);
    }
    a0 = fmaxf(a0, 0.f); a1 = fmaxf(a1, 0.f); a2 = fmaxf(a2, 0.f); a3 = fmaxf(a3, 0.f);
    ushort4 o; o.x = f2b(a0); o.y = f2b(a1); o.z = f2b(a2); o.w = f2b(a3);
    *(ushort4*)(outb + (size_t)i * DIM + f0) = o;
}

// ---------------- head: pooled mean -> logits -> log_softmax ----------------
__global__ void k_final(const float* __restrict__ pooled, const int* __restrict__ counts,
                        const float* __restrict__ Wc, const float* __restrict__ bc,
                        float* __restrict__ out) {
    int g = blockIdx.x, lane = threadIdx.x;   // 64 threads = 1 wave
    float inv = 1.0f / fmaxf((float)counts[g], 1.0f);
    const float4 pv = *(const float4*)(pooled + (size_t)g * DIM + lane * 4);
    float p0 = pv.x * inv, p1 = pv.y * inv, p2 = pv.z * inv, p3 = pv.w * inv;
    __shared__ float logits[N_CLASSES];
    int f = lane * 4;
    for (int c = 0; c < N_CLASSES; ++c) {
        float part = p0 * Wc[(f + 0) * N_CLASSES + c] + p1 * Wc[(f + 1) * N_CLASSES + c]
                   + p2 * Wc[(f + 2) * N_CLASSES + c] + p3 * Wc[(f + 3) * N_CLASSES + c];
        for (int s = 32; s > 0; s >>= 1) part += __shfl_down(part, s);
        if (lane == 0) logits[c] = part + bc[c];
    }
    __syncthreads();
    if (lane == 0) {
        float mx = logits[0];
        for (int c = 1; c < N_CLASSES; ++c) mx = fmaxf(mx, logits[c]);
        float se = 0.f;
        for (int c = 0; c < N_CLASSES; ++c) se += expf(logits[c] - mx);
        float lse = mx + logf(se);
        for (int c = 0; c < N_CLASSES; ++c) {
            out[g * N_CLASSES + c] = logits[c];
            out[N_GRAPHS * N_CLASSES + g * N_CLASSES + c] = logits[c] - lse;
        }
    }
}

// ---------------- launch ----------------
extern "C" void kernel_launch(void* const* d_in, const int* in_sizes, int n_in,
                              void* d_out, int out_size, void* d_ws, size_t ws_size,
                              hipStream_t stream) {
    const float* x    = (const float*)d_in[0];
    const int*   ei   = (const int*)d_in[1];
    const int*   src  = ei;
    const int*   dst  = ei + N_EDGES;
    const int*   batch= (const int*)d_in[2];
    const float* W1 = (const float*)d_in[3]; const float* b1 = (const float*)d_in[4];
    const float* W2 = (const float*)d_in[5]; const float* b2 = (const float*)d_in[6];
    const float* W3 = (const float*)d_in[7]; const float* b3 = (const float*)d_in[8];
    const float* Wc = (const float*)d_in[9]; const float* bc = (const float*)d_in[10];
    float* out = (float*)d_out;

    char* ws = (char*)d_ws;
    size_t off = 0;
    auto alloc = [&](size_t bytes) -> char* {
        char* p = ws + off;
        off = (off + bytes + 255) & ~(size_t)255;
        return p;
    };
    int*    deg     = (int*)alloc(N_NODES * 4);          // zeroed region start (ws+0)
    int*    fill    = (int*)alloc(N_NODES * 4);
    int*    counts  = (int*)alloc(N_GRAPHS * 4);
    float*  pooled  = (float*)alloc(N_GRAPHS * DIM * 4);
    size_t  zero_bytes = off;
    float*  dinv    = (float*)alloc(N_NODES * 4);
    int*    row_ptr = (int*)alloc((N_NODES + 1) * 4);
    int*    csr_src = (int*)alloc((size_t)N_EDGES * 4);
    float*  csr_w   = (float*)alloc((size_t)N_EDGES * 4);
    ushort* Wt1     = (ushort*)alloc(65536 * 2);
    ushort* Wt2     = (ushort*)alloc(65536 * 2);
    ushort* Wt3     = (ushort*)alloc(65536 * 2);
    ushort* xb      = (ushort*)alloc((size_t)N_NODES * DIM * 2);
    ushort* h1      = (ushort*)alloc((size_t)N_NODES * DIM * 2);
    ushort* hb      = (ushort*)alloc((size_t)N_NODES * DIM * 2);

    hipMemsetAsync(d_ws, 0, zero_bytes, stream);

    k_convert_x<<<(N_NODES * DIM / 4 + 255) / 256, 256, 0, stream>>>(x, xb, N_NODES * DIM / 4);
    k_wt<<<256, 256, 0, stream>>>(W1, Wt1);
    k_wt<<<256, 256, 0, stream>>>(W2, Wt2);
    k_wt<<<256, 256, 0, stream>>>(W3, Wt3);
    k_deg<<<(N_EDGES + 255) / 256, 256, 0, stream>>>(dst, deg);
    k_counts<<<(N_NODES + 255) / 256, 256, 0, stream>>>(batch, counts);
    k_dinv<<<(N_NODES + 255) / 256, 256, 0, stream>>>(deg, dinv);
    k_scan<<<1, 1024, 0, stream>>>(deg, row_ptr, N_NODES);
    k_fill<<<(N_EDGES + 255) / 256, 256, 0, stream>>>(src, dst, row_ptr, fill, dinv, csr_src, csr_w);

    // conv1: h1 = relu(agg(xb @ W1) + b1)
    k_gemm<<<N_NODES / 16, 256, 0, stream>>>(xb, Wt1, hb);
    k_agg<<<(N_NODES + 3) / 4, 256, 0, stream>>>(hb, row_ptr, csr_src, csr_w, dinv, b1,
                                                 nullptr, h1, nullptr, nullptr, 0);
    // conv2: xb = relu(h1 + agg(h1 @ W2) + b2)
    k_gemm<<<N_NODES / 16, 256, 0, stream>>>(h1, Wt2, hb);
    k_agg<<<(N_NODES + 3) / 4, 256, 0, stream>>>(hb, row_ptr, csr_src, csr_w, dinv, b2,
                                                 h1, xb, nullptr, nullptr, 1);
    // conv3: pooled += agg(xb @ W3) + b3
    k_gemm<<<N_NODES / 16, 256, 0, stream>>>(xb, Wt3, hb);
    k_agg<<<(N_NODES + 3) / 4, 256, 0, stream>>>(hb, row_ptr, csr_src, csr_w, dinv, b3,
                                                 nullptr, nullptr, pooled, batch, 2);

    k_final<<<N_GRAPHS, 64, 0, stream>>>(pooled, counts, Wc, bc, out);
}

// Round 2
// 524.984 us; speedup vs baseline: 1.0814x; 1.0814x over previous
//
#include <hip/hip_runtime.h>
#include <hip/hip_bf16.h>

#define N_NODES   20000
#define N_EDGES   320000
#define DIM       256
#define N_GRAPHS  64
#define N_CLASSES 10
// padded CSR capacity: every node rounds its degree up to a multiple of 4
#define CSR_CAP   (N_EDGES + 4 * N_NODES)

typedef short bf16x8 __attribute__((ext_vector_type(8)));
typedef float f32x4  __attribute__((ext_vector_type(4)));

__device__ __forceinline__ float b2f(ushort u) {
    return __uint_as_float(((unsigned)u) << 16);
}
__device__ __forceinline__ ushort f2b(float f) {
    unsigned u = __float_as_uint(f);
    u += 0x7FFF + ((u >> 16) & 1);   // round-to-nearest-even
    return (ushort)(u >> 16);
}

// ---------------- setup kernels ----------------

__global__ void k_convert_x(const float* __restrict__ x, ushort* __restrict__ xb, int n4) {
    int i = blockIdx.x * blockDim.x + threadIdx.x;
    if (i >= n4) return;
    const float4 v = ((const float4*)x)[i];
    ushort4 o; o.x = f2b(v.x); o.y = f2b(v.y); o.z = f2b(v.z); o.w = f2b(v.w);
    ((ushort4*)xb)[i] = o;
}

// Wt[n*256+k] = bf16(W[k*256+n])
__global__ void k_wt(const float* __restrict__ W, ushort* __restrict__ Wt) {
    int i = blockIdx.x * blockDim.x + threadIdx.x;   // 65536
    int n = i >> 8, k = i & 255;
    Wt[i] = f2b(W[k * 256 + n]);
}

__global__ void k_deg(const int* __restrict__ dst, int* __restrict__ deg) {
    int e = blockIdx.x * 256 + threadIdx.x;
    if (e < N_EDGES) atomicAdd(&deg[dst[e]], 1);
}

__global__ void k_counts(const int* __restrict__ batch, int* __restrict__ counts) {
    int i = blockIdx.x * 256 + threadIdx.x;
    if (i < N_NODES) atomicAdd(&counts[batch[i]], 1);
}

// dinv = rsqrt(in_deg + 1) (self-loop); pdeg = deg rounded up to multiple of 4
__global__ void k_dinv_pdeg(const int* __restrict__ deg, float* __restrict__ dinv,
                            int* __restrict__ pdeg) {
    int i = blockIdx.x * 256 + threadIdx.x;
    if (i < N_NODES) {
        int d = deg[i];
        dinv[i] = rsqrtf((float)d + 1.0f);
        pdeg[i] = (d + 3) & ~3;
    }
}

// single-block exclusive scan of pdeg -> row_ptr[0..n] (all entries multiple of 4)
__global__ void k_scan(const int* __restrict__ pdeg, int* __restrict__ row_ptr, int n) {
    __shared__ int sh[1024];
    int tid = threadIdx.x;
    int off = 0;
    int nchunk = (n + 1023) >> 10;
    for (int c = 0; c < nchunk; ++c) {
        int i = (c << 10) + tid;
        int v = (i < n) ? pdeg[i] : 0;
        sh[tid] = v;
        __syncthreads();
        for (int s = 1; s < 1024; s <<= 1) {
            int t = (tid >= s) ? sh[tid - s] : 0;
            __syncthreads();
            sh[tid] += t;
            __syncthreads();
        }
        if (i < n) row_ptr[i] = off + sh[tid] - v;   // exclusive
        off += sh[1023];
        __syncthreads();
    }
    if (tid == 0) row_ptr[n] = off;
}

// scatter edges into padded CSR. Pad slots stay (src=0, w=0.0) from the memset.
__global__ void k_fill(const int* __restrict__ src, const int* __restrict__ dst,
                       const int* __restrict__ row_ptr, int* __restrict__ fill,
                       const float* __restrict__ dinv,
                       int* __restrict__ csr_src, float* __restrict__ csr_w) {
    int e = blockIdx.x * 256 + threadIdx.x;
    if (e >= N_EDGES) return;
    int s = src[e], d = dst[e];
    int pos = atomicAdd(&fill[d], 1);
    int idx = row_ptr[d] + pos;
    csr_src[idx] = s;
    csr_w[idx]   = dinv[s] * dinv[d];
}

// ---------------- GEMM: H[M,256] = Xb[M,256] @ W (Wt is W^T, bf16) ----------------
__global__ __launch_bounds__(256) void k_gemm(const ushort* __restrict__ Xb,
                                              const ushort* __restrict__ Wt,
                                              ushort* __restrict__ H) {
    int wave = threadIdx.x >> 6;
    int lane = threadIdx.x & 63;
    int m0 = blockIdx.x * 16;
    int n0 = wave * 64;
    int rl = lane & 15;
    int kq = (lane >> 4) * 8;

    const ushort* aptr = Xb + (size_t)(m0 + rl) * DIM + kq;
    f32x4 acc[4] = {};

#pragma unroll
    for (int kk = 0; kk < 8; ++kk) {
        int k0 = kk * 32;
        bf16x8 a = *(const bf16x8*)(aptr + k0);
#pragma unroll
        for (int nb = 0; nb < 4; ++nb) {
            const ushort* bptr = Wt + (size_t)(n0 + nb * 16 + rl) * DIM + k0 + kq;
            bf16x8 b = *(const bf16x8*)bptr;
            acc[nb] = __builtin_amdgcn_mfma_f32_16x16x32_bf16(a, b, acc[nb], 0, 0, 0);
        }
    }
    int crow = m0 + (lane >> 4) * 4;
    int ccol = n0 + rl;
#pragma unroll
    for (int nb = 0; nb < 4; ++nb)
#pragma unroll
        for (int r = 0; r < 4; ++r)
            H[(size_t)(crow + r) * DIM + ccol + nb * 16] = f2b(acc[nb][r]);
}

// ---------------- aggregation: one wave per dst node, 4 edges in flight ----------------
// mode 0: relu(acc+b) -> outb
// mode 1: relu(prev + acc + b) -> outb
// mode 2: atomicAdd pooled[batch[i]] += acc + b
__global__ __launch_bounds__(256) void k_agg(
    const ushort* __restrict__ H, const int* __restrict__ row_ptr,
    const int* __restrict__ csr_src, const float* __restrict__ csr_w,
    const float* __restrict__ dinv, const float* __restrict__ bias,
    const ushort* __restrict__ prev, ushort* __restrict__ outb,
    float* __restrict__ pooled, const int* __restrict__ batch, int mode) {
    int wave = threadIdx.x >> 6, lane = threadIdx.x & 63;
    int i = blockIdx.x * 4 + wave;
    if (i >= N_NODES) return;
    int f0 = lane * 4;
    float di = dinv[i];
    float wself = di * di;   // self-loop norm
    ushort4 hv = *(const ushort4*)(H + (size_t)i * DIM + f0);
    float a0 = b2f(hv.x) * wself, a1 = b2f(hv.y) * wself,
          a2 = b2f(hv.z) * wself, a3 = b2f(hv.w) * wself;
    int e0 = row_ptr[i], e1 = row_ptr[i + 1];
    if (e0 < e1) {
        // software-pipelined: prefetch next index/weight block while gathering rows
        int4   s4 = *(const int4*)(csr_src + e0);
        float4 w4 = *(const float4*)(csr_w + e0);
        for (int e = e0; e < e1;) {
            int4 cs = s4; float4 cw = w4;
            int en = e + 4;
            if (en < e1) {
                s4 = *(const int4*)(csr_src + en);
                w4 = *(const float4*)(csr_w + en);
            }
            // 4 independent row gathers in flight
            ushort4 v0 = *(const ushort4*)(H + (size_t)cs.x * DIM + f0);
            ushort4 v1 = *(const ushort4*)(H + (size_t)cs.y * DIM + f0);
            ushort4 v2 = *(const ushort4*)(H + (size_t)cs.z * DIM + f0);
            ushort4 v3 = *(const ushort4*)(H + (size_t)cs.w * DIM + f0);
            a0 += cw.x * b2f(v0.x) + cw.y * b2f(v1.x) + cw.z * b2f(v2.x) + cw.w * b2f(v3.x);
            a1 += cw.x * b2f(v0.y) + cw.y * b2f(v1.y) + cw.z * b2f(v2.y) + cw.w * b2f(v3.y);
            a2 += cw.x * b2f(v0.z) + cw.y * b2f(v1.z) + cw.z * b2f(v2.z) + cw.w * b2f(v3.z);
            a3 += cw.x * b2f(v0.w) + cw.y * b2f(v1.w) + cw.z * b2f(v2.w) + cw.w * b2f(v3.w);
            e = en;
        }
    }
    const float4 bb = *(const float4*)(bias + f0);
    a0 += bb.x; a1 += bb.y; a2 += bb.z; a3 += bb.w;
    if (mode == 2) {
        int g = batch[i];
        float* p = pooled + (size_t)g * DIM + f0;
        atomicAdd(p + 0, a0); atomicAdd(p + 1, a1);
        atomicAdd(p + 2, a2); atomicAdd(p + 3, a3);
        return;
    }
    if (mode == 1) {
        ushort4 pv = *(const ushort4*)(prev + (size_t)i * DIM + f0);
        a0 += b2f(pv.x); a1 += b2f(pv.y); a2 += b2f(pv.z); a3 += b2f(pv.w);
    }
    a0 = fmaxf(a0, 0.f); a1 = fmaxf(a1, 0.f); a2 = fmaxf(a2, 0.f); a3 = fmaxf(a3, 0.f);
    ushort4 o; o.x = f2b(a0); o.y = f2b(a1); o.z = f2b(a2); o.w = f2b(a3);
    *(ushort4*)(outb + (size_t)i * DIM + f0) = o;
}

// ---------------- head: pooled mean -> logits -> log_softmax ----------------
__global__ void k_final(const float* __restrict__ pooled, const int* __restrict__ counts,
                        const float* __restrict__ Wc, const float* __restrict__ bc,
                        float* __restrict__ out) {
    int g = blockIdx.x, lane = threadIdx.x;   // 64 threads = 1 wave
    float inv = 1.0f / fmaxf((float)counts[g], 1.0f);
    const float4 pv = *(const float4*)(pooled + (size_t)g * DIM + lane * 4);
    float p0 = pv.x * inv, p1 = pv.y * inv, p2 = pv.z * inv, p3 = pv.w * inv;
    __shared__ float logits[N_CLASSES];
    int f = lane * 4;
    for (int c = 0; c < N_CLASSES; ++c) {
        float part = p0 * Wc[(f + 0) * N_CLASSES + c] + p1 * Wc[(f + 1) * N_CLASSES + c]
                   + p2 * Wc[(f + 2) * N_CLASSES + c] + p3 * Wc[(f + 3) * N_CLASSES + c];
        for (int s = 32; s > 0; s >>= 1) part += __shfl_down(part, s);
        if (lane == 0) logits[c] = part + bc[c];
    }
    __syncthreads();
    if (lane == 0) {
        float mx = logits[0];
        for (int c = 1; c < N_CLASSES; ++c) mx = fmaxf(mx, logits[c]);
        float se = 0.f;
        for (int c = 0; c < N_CLASSES; ++c) se += expf(logits[c] - mx);
        float lse = mx + logf(se);
        for (int c = 0; c < N_CLASSES; ++c) {
            out[g * N_CLASSES + c] = logits[c];
            out[N_GRAPHS * N_CLASSES + g * N_CLASSES + c] = logits[c] - lse;
        }
    }
}

// ---------------- launch ----------------
extern "C" void kernel_launch(void* const* d_in, const int* in_sizes, int n_in,
                              void* d_out, int out_size, void* d_ws, size_t ws_size,
                              hipStream_t stream) {
    const float* x    = (const float*)d_in[0];
    const int*   ei   = (const int*)d_in[1];
    const int*   src  = ei;
    const int*   dst  = ei + N_EDGES;
    const int*   batch= (const int*)d_in[2];
    const float* W1 = (const float*)d_in[3]; const float* b1 = (const float*)d_in[4];
    const float* W2 = (const float*)d_in[5]; const float* b2 = (const float*)d_in[6];
    const float* W3 = (const float*)d_in[7]; const float* b3 = (const float*)d_in[8];
    const float* Wc = (const float*)d_in[9]; const float* bc = (const float*)d_in[10];
    float* out = (float*)d_out;

    char* ws = (char*)d_ws;
    size_t off = 0;
    auto alloc = [&](size_t bytes) -> char* {
        char* p = ws + off;
        off = (off + bytes + 255) & ~(size_t)255;
        return p;
    };
    // ---- zeroed region (one memset) ----
    int*    deg     = (int*)alloc(N_NODES * 4);
    int*    fill    = (int*)alloc(N_NODES * 4);
    int*    counts  = (int*)alloc(N_GRAPHS * 4);
    float*  pooled  = (float*)alloc(N_GRAPHS * DIM * 4);
    int*    csr_src = (int*)alloc((size_t)CSR_CAP * 4);   // pad slots must be 0
    float*  csr_w   = (float*)alloc((size_t)CSR_CAP * 4); // pad slots must be 0.0f
    size_t  zero_bytes = off;
    // ---- uninitialized scratch ----
    float*  dinv    = (float*)alloc(N_NODES * 4);
    int*    pdeg    = (int*)alloc(N_NODES * 4);
    int*    row_ptr = (int*)alloc((N_NODES + 1) * 4);
    ushort* Wt1     = (ushort*)alloc(65536 * 2);
    ushort* Wt2     = (ushort*)alloc(65536 * 2);
    ushort* Wt3     = (ushort*)alloc(65536 * 2);
    ushort* xb      = (ushort*)alloc((size_t)N_NODES * DIM * 2);
    ushort* h1      = (ushort*)alloc((size_t)N_NODES * DIM * 2);
    ushort* hb      = (ushort*)alloc((size_t)N_NODES * DIM * 2);

    hipMemsetAsync(d_ws, 0, zero_bytes, stream);

    k_convert_x<<<(N_NODES * DIM / 4 + 255) / 256, 256, 0, stream>>>(x, xb, N_NODES * DIM / 4);
    k_wt<<<256, 256, 0, stream>>>(W1, Wt1);
    k_wt<<<256, 256, 0, stream>>>(W2, Wt2);
    k_wt<<<256, 256, 0, stream>>>(W3, Wt3);
    k_deg<<<(N_EDGES + 255) / 256, 256, 0, stream>>>(dst, deg);
    k_counts<<<(N_NODES + 255) / 256, 256, 0, stream>>>(batch, counts);
    k_dinv_pdeg<<<(N_NODES + 255) / 256, 256, 0, stream>>>(deg, dinv, pdeg);
    k_scan<<<1, 1024, 0, stream>>>(pdeg, row_ptr, N_NODES);
    k_fill<<<(N_EDGES + 255) / 256, 256, 0, stream>>>(src, dst, row_ptr, fill, dinv, csr_src, csr_w);

    // conv1: h1 = relu(agg(xb @ W1) + b1)
    k_gemm<<<N_NODES / 16, 256, 0, stream>>>(xb, Wt1, hb);
    k_agg<<<(N_NODES + 3) / 4, 256, 0, stream>>>(hb, row_ptr, csr_src, csr_w, dinv, b1,
                                                 nullptr, h1, nullptr, nullptr, 0);
    // conv2: xb = relu(h1 + agg(h1 @ W2) + b2)
    k_gemm<<<N_NODES / 16, 256, 0, stream>>>(h1, Wt2, hb);
    k_agg<<<(N_NODES + 3) / 4, 256, 0, stream>>>(hb, row_ptr, csr_src, csr_w, dinv, b2,
                                                 h1, xb, nullptr, nullptr, 1);
    // conv3: pooled += agg(xb @ W3) + b3
    k_gemm<<<N_NODES / 16, 256, 0, stream>>>(xb, Wt3, hb);
    k_agg<<<(N_NODES + 3) / 4, 256, 0, stream>>>(hb, row_ptr, csr_src, csr_w, dinv, b3,
                                                 nullptr, nullptr, pooled, batch, 2);

    k_final<<<N_GRAPHS, 64, 0, stream>>>(pooled, counts, Wc, bc, out);
}

// Round 3
// 524.858 us; speedup vs baseline: 1.0817x; 1.0002x over previous
//
#include <hip/hip_runtime.h>
#include <hip/hip_bf16.h>

#define N_NODES   20000
#define N_EDGES   320000
#define DIM       256
#define N_GRAPHS  64
#define N_CLASSES 10
// padded CSR capacity: every node rounds its degree up to a multiple of 8
#define CSR_CAP   (N_EDGES + 8 * N_NODES)

typedef short bf16x8 __attribute__((ext_vector_type(8)));
typedef float f32x4  __attribute__((ext_vector_type(4)));

__device__ __forceinline__ float b2f(ushort u) {
    return __uint_as_float(((unsigned)u) << 16);
}
__device__ __forceinline__ ushort f2b(float f) {
    unsigned u = __float_as_uint(f);
    u += 0x7FFF + ((u >> 16) & 1);   // round-to-nearest-even
    return (ushort)(u >> 16);
}

// ---------------- setup kernels ----------------

__global__ void k_convert_x(const float* __restrict__ x, ushort* __restrict__ xb, int n4) {
    int i = blockIdx.x * blockDim.x + threadIdx.x;
    if (i >= n4) return;
    const float4 v = ((const float4*)x)[i];
    ushort4 o; o.x = f2b(v.x); o.y = f2b(v.y); o.z = f2b(v.z); o.w = f2b(v.w);
    ((ushort4*)xb)[i] = o;
}

// Wt[n*256+k] = bf16(W[k*256+n])
__global__ void k_wt(const float* __restrict__ W, ushort* __restrict__ Wt) {
    int i = blockIdx.x * blockDim.x + threadIdx.x;   // 65536
    int n = i >> 8, k = i & 255;
    Wt[i] = f2b(W[k * 256 + n]);
}

__global__ void k_deg(const int* __restrict__ dst, int* __restrict__ deg) {
    int e = blockIdx.x * 256 + threadIdx.x;
    if (e < N_EDGES) atomicAdd(&deg[dst[e]], 1);
}

__global__ void k_counts(const int* __restrict__ batch, int* __restrict__ counts) {
    int i = blockIdx.x * 256 + threadIdx.x;
    if (i < N_NODES) atomicAdd(&counts[batch[i]], 1);
}

// dinv = rsqrt(in_deg + 1) (self-loop); pdeg = deg rounded up to multiple of 8
__global__ void k_dinv_pdeg(const int* __restrict__ deg, float* __restrict__ dinv,
                            int* __restrict__ pdeg) {
    int i = blockIdx.x * 256 + threadIdx.x;
    if (i < N_NODES) {
        int d = deg[i];
        dinv[i] = rsqrtf((float)d + 1.0f);
        pdeg[i] = (d + 7) & ~7;
    }
}

// single-block exclusive scan of pdeg -> row_ptr[0..n] (all entries multiple of 8)
__global__ void k_scan(const int* __restrict__ pdeg, int* __restrict__ row_ptr, int n) {
    __shared__ int sh[1024];
    int tid = threadIdx.x;
    int off = 0;
    int nchunk = (n + 1023) >> 10;
    for (int c = 0; c < nchunk; ++c) {
        int i = (c << 10) + tid;
        int v = (i < n) ? pdeg[i] : 0;
        sh[tid] = v;
        __syncthreads();
        for (int s = 1; s < 1024; s <<= 1) {
            int t = (tid >= s) ? sh[tid - s] : 0;
            __syncthreads();
            sh[tid] += t;
            __syncthreads();
        }
        if (i < n) row_ptr[i] = off + sh[tid] - v;   // exclusive
        off += sh[1023];
        __syncthreads();
    }
    if (tid == 0) row_ptr[n] = off;
}

// scatter edges into padded CSR. Pad slots stay (src=0, w=0.0) from the memset.
__global__ void k_fill(const int* __restrict__ src, const int* __restrict__ dst,
                       const int* __restrict__ row_ptr, int* __restrict__ fill,
                       const float* __restrict__ dinv,
                       int* __restrict__ csr_src, float* __restrict__ csr_w) {
    int e = blockIdx.x * 256 + threadIdx.x;
    if (e >= N_EDGES) return;
    int s = src[e], d = dst[e];
    int pos = atomicAdd(&fill[d], 1);
    int idx = row_ptr[d] + pos;
    csr_src[idx] = s;
    csr_w[idx]   = dinv[s] * dinv[d];
}

// ---------------- GEMM: H[M,256] = Xb[M,256] @ W (Wt is W^T, bf16) ----------------
__global__ __launch_bounds__(256) void k_gemm(const ushort* __restrict__ Xb,
                                              const ushort* __restrict__ Wt,
                                              ushort* __restrict__ H) {
    int wave = threadIdx.x >> 6;
    int lane = threadIdx.x & 63;
    int m0 = blockIdx.x * 16;
    int n0 = wave * 64;
    int rl = lane & 15;
    int kq = (lane >> 4) * 8;

    const ushort* aptr = Xb + (size_t)(m0 + rl) * DIM + kq;
    f32x4 acc[4] = {};

#pragma unroll
    for (int kk = 0; kk < 8; ++kk) {
        int k0 = kk * 32;
        bf16x8 a = *(const bf16x8*)(aptr + k0);
#pragma unroll
        for (int nb = 0; nb < 4; ++nb) {
            const ushort* bptr = Wt + (size_t)(n0 + nb * 16 + rl) * DIM + k0 + kq;
            bf16x8 b = *(const bf16x8*)bptr;
            acc[nb] = __builtin_amdgcn_mfma_f32_16x16x32_bf16(a, b, acc[nb], 0, 0, 0);
        }
    }
    int crow = m0 + (lane >> 4) * 4;
    int ccol = n0 + rl;
#pragma unroll
    for (int nb = 0; nb < 4; ++nb)
#pragma unroll
        for (int r = 0; r < 4; ++r)
            H[(size_t)(crow + r) * DIM + ccol + nb * 16] = f2b(acc[nb][r]);
}

// ---------------- aggregation: one wave per dst node, 8 gathers in flight ----------------
// __launch_bounds__(256, 2): cap occupancy at 2 blocks/CU so the compiler gets
// ~128 VGPRs — at (256,default) it allocated 24 VGPRs and re-serialized the
// gathers (R2 post-mortem: 229 cyc/gather, MLP~2/CU).
// mode 0: relu(acc+b) -> outb ; mode 1: relu(prev+acc+b) -> outb
// mode 2: atomicAdd pooled[batch[i]] += acc + b
__global__ __launch_bounds__(256, 2) void k_agg(
    const ushort* __restrict__ H, const int* __restrict__ row_ptr,
    const int* __restrict__ csr_src, const float* __restrict__ csr_w,
    const float* __restrict__ dinv, const float* __restrict__ bias,
    const ushort* __restrict__ prev, ushort* __restrict__ outb,
    float* __restrict__ pooled, const int* __restrict__ batch, int mode) {
    int wave = threadIdx.x >> 6, lane = threadIdx.x & 63;
    int i = blockIdx.x * 4 + wave;
    if (i >= N_NODES) return;
    int f0 = lane * 4;
    const ushort* Hf = H + f0;
    float di = dinv[i];
    float wself = di * di;   // self-loop norm
    ushort4 hv = *(const ushort4*)(Hf + (size_t)i * DIM);
    float a0 = b2f(hv.x) * wself, a1 = b2f(hv.y) * wself,
          a2 = b2f(hv.z) * wself, a3 = b2f(hv.w) * wself;
    int e0 = row_ptr[i], e1 = row_ptr[i + 1];
    if (e0 < e1) {
        // prefetch first index/weight block
        int4   sA = *(const int4*)(csr_src + e0);
        int4   sB = *(const int4*)(csr_src + e0 + 4);
        float4 wA = *(const float4*)(csr_w + e0);
        float4 wB = *(const float4*)(csr_w + e0 + 4);
        for (int e = e0; e < e1;) {
            int4 cA = sA, cB = sB; float4 xA = wA, xB = wB;
            int en = e + 8;
            if (en < e1) {
                sA = *(const int4*)(csr_src + en);
                sB = *(const int4*)(csr_src + en + 4);
                wA = *(const float4*)(csr_w + en);
                wB = *(const float4*)(csr_w + en + 4);
            }
            // 8 independent 512B row gathers in flight
            ushort4 v0 = *(const ushort4*)(Hf + (size_t)cA.x * DIM);
            ushort4 v1 = *(const ushort4*)(Hf + (size_t)cA.y * DIM);
            ushort4 v2 = *(const ushort4*)(Hf + (size_t)cA.z * DIM);
            ushort4 v3 = *(const ushort4*)(Hf + (size_t)cA.w * DIM);
            ushort4 v4 = *(const ushort4*)(Hf + (size_t)cB.x * DIM);
            ushort4 v5 = *(const ushort4*)(Hf + (size_t)cB.y * DIM);
            ushort4 v6 = *(const ushort4*)(Hf + (size_t)cB.z * DIM);
            ushort4 v7 = *(const ushort4*)(Hf + (size_t)cB.w * DIM);
            a0 += xA.x * b2f(v0.x) + xA.y * b2f(v1.x) + xA.z * b2f(v2.x) + xA.w * b2f(v3.x)
                + xB.x * b2f(v4.x) + xB.y * b2f(v5.x) + xB.z * b2f(v6.x) + xB.w * b2f(v7.x);
            a1 += xA.x * b2f(v0.y) + xA.y * b2f(v1.y) + xA.z * b2f(v2.y) + xA.w * b2f(v3.y)
                + xB.x * b2f(v4.y) + xB.y * b2f(v5.y) + xB.z * b2f(v6.y) + xB.w * b2f(v7.y);
            a2 += xA.x * b2f(v0.z) + xA.y * b2f(v1.z) + xA.z * b2f(v2.z) + xA.w * b2f(v3.z)
                + xB.x * b2f(v4.z) + xB.y * b2f(v5.z) + xB.z * b2f(v6.z) + xB.w * b2f(v7.z);
            a3 += xA.x * b2f(v0.w) + xA.y * b2f(v1.w) + xA.z * b2f(v2.w) + xA.w * b2f(v3.w)
                + xB.x * b2f(v4.w) + xB.y * b2f(v5.w) + xB.z * b2f(v6.w) + xB.w * b2f(v7.w);
            e = en;
        }
    }
    const float4 bb = *(const float4*)(bias + f0);
    a0 += bb.x; a1 += bb.y; a2 += bb.z; a3 += bb.w;
    if (mode == 2) {
        int g = batch[i];
        float* p = pooled + (size_t)g * DIM + f0;
        atomicAdd(p + 0, a0); atomicAdd(p + 1, a1);
        atomicAdd(p + 2, a2); atomicAdd(p + 3, a3);
        return;
    }
    if (mode == 1) {
        ushort4 pv = *(const ushort4*)(prev + (size_t)i * DIM + f0);
        a0 += b2f(pv.x); a1 += b2f(pv.y); a2 += b2f(pv.z); a3 += b2f(pv.w);
    }
    a0 = fmaxf(a0, 0.f); a1 = fmaxf(a1, 0.f); a2 = fmaxf(a2, 0.f); a3 = fmaxf(a3, 0.f);
    ushort4 o; o.x = f2b(a0); o.y = f2b(a1); o.z = f2b(a2); o.w = f2b(a3);
    *(ushort4*)(outb + (size_t)i * DIM + f0) = o;
}

// ---------------- head: pooled mean -> logits -> log_softmax ----------------
__global__ void k_final(const float* __restrict__ pooled, const int* __restrict__ counts,
                        const float* __restrict__ Wc, const float* __restrict__ bc,
                        float* __restrict__ out) {
    int g = blockIdx.x, lane = threadIdx.x;   // 64 threads = 1 wave
    float inv = 1.0f / fmaxf((float)counts[g], 1.0f);
    const float4 pv = *(const float4*)(pooled + (size_t)g * DIM + lane * 4);
    float p0 = pv.x * inv, p1 = pv.y * inv, p2 = pv.z * inv, p3 = pv.w * inv;
    __shared__ float logits[N_CLASSES];
    int f = lane * 4;
    for (int c = 0; c < N_CLASSES; ++c) {
        float part = p0 * Wc[(f + 0) * N_CLASSES + c] + p1 * Wc[(f + 1) * N_CLASSES + c]
                   + p2 * Wc[(f + 2) * N_CLASSES + c] + p3 * Wc[(f + 3) * N_CLASSES + c];
        for (int s = 32; s > 0; s >>= 1) part += __shfl_down(part, s);
        if (lane == 0) logits[c] = part + bc[c];
    }
    __syncthreads();
    if (lane == 0) {
        float mx = logits[0];
        for (int c = 1; c < N_CLASSES; ++c) mx = fmaxf(mx, logits[c]);
        float se = 0.f;
        for (int c = 0; c < N_CLASSES; ++c) se += expf(logits[c] - mx);
        float lse = mx + logf(se);
        for (int c = 0; c < N_CLASSES; ++c) {
            out[g * N_CLASSES + c] = logits[c];
            out[N_GRAPHS * N_CLASSES + g * N_CLASSES + c] = logits[c] - lse;
        }
    }
}

// ---------------- launch ----------------
extern "C" void kernel_launch(void* const* d_in, const int* in_sizes, int n_in,
                              void* d_out, int out_size, void* d_ws, size_t ws_size,
                              hipStream_t stream) {
    const float* x    = (const float*)d_in[0];
    const int*   ei   = (const int*)d_in[1];
    const int*   src  = ei;
    const int*   dst  = ei + N_EDGES;
    const int*   batch= (const int*)d_in[2];
    const float* W1 = (const float*)d_in[3]; const float* b1 = (const float*)d_in[4];
    const float* W2 = (const float*)d_in[5]; const float* b2 = (const float*)d_in[6];
    const float* W3 = (const float*)d_in[7]; const float* b3 = (const float*)d_in[8];
    const float* Wc = (const float*)d_in[9]; const float* bc = (const float*)d_in[10];
    float* out = (float*)d_out;

    char* ws = (char*)d_ws;
    size_t off = 0;
    auto alloc = [&](size_t bytes) -> char* {
        char* p = ws + off;
        off = (off + bytes + 255) & ~(size_t)255;
        return p;
    };
    // ---- zeroed region (one memset) ----
    int*    deg     = (int*)alloc(N_NODES * 4);
    int*    fill    = (int*)alloc(N_NODES * 4);
    int*    counts  = (int*)alloc(N_GRAPHS * 4);
    float*  pooled  = (float*)alloc(N_GRAPHS * DIM * 4);
    int*    csr_src = (int*)alloc((size_t)CSR_CAP * 4);   // pad slots must be 0
    float*  csr_w   = (float*)alloc((size_t)CSR_CAP * 4); // pad slots must be 0.0f
    size_t  zero_bytes = off;
    // ---- uninitialized scratch ----
    float*  dinv    = (float*)alloc(N_NODES * 4);
    int*    pdeg    = (int*)alloc(N_NODES * 4);
    int*    row_ptr = (int*)alloc((N_NODES + 1) * 4);
    ushort* Wt1     = (ushort*)alloc(65536 * 2);
    ushort* Wt2     = (ushort*)alloc(65536 * 2);
    ushort* Wt3     = (ushort*)alloc(65536 * 2);
    ushort* xb      = (ushort*)alloc((size_t)N_NODES * DIM * 2);
    ushort* h1      = (ushort*)alloc((size_t)N_NODES * DIM * 2);
    ushort* hb      = (ushort*)alloc((size_t)N_NODES * DIM * 2);

    hipMemsetAsync(d_ws, 0, zero_bytes, stream);

    k_convert_x<<<(N_NODES * DIM / 4 + 255) / 256, 256, 0, stream>>>(x, xb, N_NODES * DIM / 4);
    k_wt<<<256, 256, 0, stream>>>(W1, Wt1);
    k_wt<<<256, 256, 0, stream>>>(W2, Wt2);
    k_wt<<<256, 256, 0, stream>>>(W3, Wt3);
    k_deg<<<(N_EDGES + 255) / 256, 256, 0, stream>>>(dst, deg);
    k_counts<<<(N_NODES + 255) / 256, 256, 0, stream>>>(batch, counts);
    k_dinv_pdeg<<<(N_NODES + 255) / 256, 256, 0, stream>>>(deg, dinv, pdeg);
    k_scan<<<1, 1024, 0, stream>>>(pdeg, row_ptr, N_NODES);
    k_fill<<<(N_EDGES + 255) / 256, 256, 0, stream>>>(src, dst, row_ptr, fill, dinv, csr_src, csr_w);

    // conv1: h1 = relu(agg(xb @ W1) + b1)
    k_gemm<<<N_NODES / 16, 256, 0, stream>>>(xb, Wt1, hb);
    k_agg<<<(N_NODES + 3) / 4, 256, 0, stream>>>(hb, row_ptr, csr_src, csr_w, dinv, b1,
                                                 nullptr, h1, nullptr, nullptr, 0);
    // conv2: xb = relu(h1 + agg(h1 @ W2) + b2)
    k_gemm<<<N_NODES / 16, 256, 0, stream>>>(h1, Wt2, hb);
    k_agg<<<(N_NODES + 3) / 4, 256, 0, stream>>>(hb, row_ptr, csr_src, csr_w, dinv, b2,
                                                 h1, xb, nullptr, nullptr, 1);
    // conv3: pooled += agg(xb @ W3) + b3
    k_gemm<<<N_NODES / 16, 256, 0, stream>>>(xb, Wt3, hb);
    k_agg<<<(N_NODES + 3) / 4, 256, 0, stream>>>(hb, row_ptr, csr_src, csr_w, dinv, b3,
                                                 nullptr, nullptr, pooled, batch, 2);

    k_final<<<N_GRAPHS, 64, 0, stream>>>(pooled, counts, Wc, bc, out);
}